// Round 3
// baseline (590.533 us; speedup 1.0000x reference)
//
#include <hip/hip_runtime.h>
#include <cfloat>
#include <cmath>

#define B_   8
#define N_   8192
#define S_   2048
#define C1_  128
#define C2_  256
#define T_   256
#define CIN_ 384
#define CO_  256

#define KCH  8           // knn S-chunks
#define KCS  (S_ / KCH)  // 256 candidates per chunk
#define KQB  512         // queries per knn block (256 thr x 2 queries)

typedef __attribute__((ext_vector_type(8))) short short8;
typedef __attribute__((ext_vector_type(4))) float f32x4;

// ---------- helpers ----------
__device__ __forceinline__ float bf2f(unsigned short u) {
    union { unsigned int i; float f; } v; v.i = ((unsigned int)u) << 16; return v.f;
}
__device__ __forceinline__ unsigned short f2bf(float f) {
    union { float f; unsigned int i; } v; v.f = f;
    unsigned int i = v.i;
    unsigned int r = i + 0x7FFFu + ((i >> 16) & 1u);   // RNE
    return (unsigned short)(r >> 16);
}
__device__ __forceinline__ float gelu_f(float x) {
    return 0.5f * x * (1.0f + erff(x * 0.70710678118654752440f));
}
__device__ __forceinline__ void async16(const void* g, void* l) {
    __builtin_amdgcn_global_load_lds((const __attribute__((address_space(1))) void*)g,
                                     (__attribute__((address_space(3))) void*)l, 16, 0, 0);
}

// ---------- ws layout (bytes) ----------
#define OFF_TE1   0u          // 8*384*4 = 12288
#define OFF_TE2   16384u      // 8*256*4 = 8192
#define OFF_STATS 24576u      // 4 x 256 floats (sum1, sq1, sum2, sq2)
#define OFF_BN1   28672u
#define OFF_BN2   30720u
#define OFF_IDX   32768u      // 65536*3*4 = 786432
#define OFF_WTS   819200u     // 786432
#define OFF_WC1   1605632u    // 98304*2
#define OFF_WC2   1802240u    // 65536*2
#define OFF_P2T   2097152u    // 8*2048*256*2 = 8388608 (bf16)
#define OFF_X1    10485760u   // 8*8192*384*2 = 50331648 (bf16; Z reuses; knn partials reuse)
#define OFF_Y     60817408u   // 8*8192*256*2 = 33554432 (bf16)
// knn partials live inside X1 region (consumed by merge before build_x1 writes X1)
#define OFF_PD    OFF_X1                    // 8*65536*3*4 = 6291456
#define OFF_PI    (OFF_X1 + 6291456u)       // 6291456

// ---------- weight fp32 -> bf16 ----------
__global__ __launch_bounds__(256) void wcvt_kernel(
    const float* __restrict__ w1, const float* __restrict__ w2,
    unsigned short* __restrict__ o1, unsigned short* __restrict__ o2)
{
    int g = blockIdx.x * 256 + threadIdx.x;          // grid 384*256 = 98304
    o1[g] = f2bf(w1[g]);
    if (g < CO_ * CO_) o2[g] = f2bf(w2[g]);
}

// ---------- te1/te2 ----------
__global__ __launch_bounds__(640) void te_kernel(
    const float* __restrict__ t_embed,
    const float* __restrict__ w_t1, const float* __restrict__ b_t1,
    const float* __restrict__ w_t2, const float* __restrict__ b_t2,
    float* __restrict__ te1, float* __restrict__ te2)
{
    __shared__ float gt[T_];
    int b = blockIdx.x, t = threadIdx.x;
    if (t < T_) gt[t] = gelu_f(t_embed[b * T_ + t]);
    __syncthreads();
    if (t < CIN_) {
        const float* w = w_t1 + t * T_;
        float s = 0.f;
        for (int k = 0; k < T_; ++k) s += gt[k] * w[k];
        te1[b * CIN_ + t] = s + b_t1[t];
    } else {
        int o = t - CIN_;
        const float* w = w_t2 + o * T_;
        float s = 0.f;
        for (int k = 0; k < T_; ++k) s += gt[k] * w[k];
        te2[b * CO_ + o] = s + b_t2[o];
    }
}

// ---------- 3-NN partials: per S-chunk top-3 ----------
// grid (N_/KQB, KCH, B_), 256 threads, 2 queries/thread
__global__ __launch_bounds__(256) void knn_part_kernel(
    const float* __restrict__ xyz1, const float* __restrict__ xyz2,
    float* __restrict__ pd, int* __restrict__ pi)
{
    __shared__ float4 sp[KCS];   // 4 KB
    int b = blockIdx.z, ch = blockIdx.y, tid = threadIdx.x;
    int s0 = ch * KCS;
    {
        int gs = s0 + tid;       // KCS == 256 == blockDim
        float x = xyz2[(b * S_ + gs) * 3 + 0];
        float y = xyz2[(b * S_ + gs) * 3 + 1];
        float z = xyz2[(b * S_ + gs) * 3 + 2];
        sp[tid] = make_float4(x, y, z, x * x + y * y + z * z);
    }
    __syncthreads();

    float x1[2], y1[2], z1[2], n1[2];
    float d1[2], d2[2], d3[2];
    int   i1[2], i2[2], i3[2];
    #pragma unroll
    for (int qq = 0; qq < 2; ++qq) {
        int n = blockIdx.x * KQB + qq * 256 + tid;
        x1[qq] = xyz1[(b * N_ + n) * 3 + 0];
        y1[qq] = xyz1[(b * N_ + n) * 3 + 1];
        z1[qq] = xyz1[(b * N_ + n) * 3 + 2];
        n1[qq] = x1[qq] * x1[qq] + y1[qq] * y1[qq] + z1[qq] * z1[qq];
        d1[qq] = FLT_MAX; d2[qq] = FLT_MAX; d3[qq] = FLT_MAX;
        i1[qq] = 0; i2[qq] = 0; i3[qq] = 0;
    }

    #pragma unroll 2
    for (int s = 0; s < KCS; ++s) {
        float4 p = sp[s];
        int gi = s0 + s;
        #pragma unroll
        for (int qq = 0; qq < 2; ++qq) {
            float dot = x1[qq] * p.x + y1[qq] * p.y + z1[qq] * p.z;
            float d = (n1[qq] + p.w) - 2.0f * dot;   // exact same expr as r2 (passed)
            if (d < d3[qq]) {
                if (d < d2[qq]) {
                    d3[qq] = d2[qq]; i3[qq] = i2[qq];
                    if (d < d1[qq]) { d2[qq] = d1[qq]; i2[qq] = i1[qq]; d1[qq] = d; i1[qq] = gi; }
                    else            { d2[qq] = d;      i2[qq] = gi; }
                } else { d3[qq] = d; i3[qq] = gi; }
            }
        }
    }

    #pragma unroll
    for (int qq = 0; qq < 2; ++qq) {
        int n = blockIdx.x * KQB + qq * 256 + tid;
        size_t pb = (((size_t)b * KCH + ch) * N_ + n) * 3;
        pd[pb + 0] = d1[qq]; pd[pb + 1] = d2[qq]; pd[pb + 2] = d3[qq];
        pi[pb + 0] = i1[qq]; pi[pb + 1] = i2[qq]; pi[pb + 2] = i3[qq];
    }
}

// ---------- merge chunk partials -> idx/wts ----------
__global__ __launch_bounds__(256) void knn_merge_kernel(
    const float* __restrict__ pd, const int* __restrict__ pi,
    int* __restrict__ idx, float* __restrict__ wts)
{
    int g = blockIdx.x * 256 + threadIdx.x;   // 65536
    int b = g >> 13, n = g & (N_ - 1);
    float d1 = FLT_MAX, d2 = FLT_MAX, d3 = FLT_MAX;
    int   i1 = 0, i2 = 0, i3 = 0;
    // ascending chunk order + ascending rank + strict '<' preserves
    // global earliest-index tie semantics of sequential scan / lax.top_k
    for (int ch = 0; ch < KCH; ++ch) {
        size_t pb = (((size_t)b * KCH + ch) * N_ + n) * 3;
        #pragma unroll
        for (int k = 0; k < 3; ++k) {
            float d = pd[pb + k];
            int   s = pi[pb + k];
            if (d < d3) {
                if (d < d2) {
                    d3 = d2; i3 = i2;
                    if (d < d1) { d2 = d1; i2 = i1; d1 = d; i1 = s; }
                    else        { d2 = d;  i2 = s; }
                } else { d3 = d; i3 = s; }
            }
        }
    }
    float r1 = 1.0f / (d1 + 1e-8f);
    float r2 = 1.0f / (d2 + 1e-8f);
    float r3 = 1.0f / (d3 + 1e-8f);
    float rs = 1.0f / (r1 + r2 + r3);
    size_t base = (size_t)g * 3;
    idx[base] = i1; idx[base + 1] = i2; idx[base + 2] = i3;
    wts[base] = r1 * rs; wts[base + 1] = r2 * rs; wts[base + 2] = r3 * rs;
}

// ---------- transpose points2 (B,C2,S) fp32 -> (B,S,C2) bf16 ----------
__global__ __launch_bounds__(256) void transpose_p2(
    const float* __restrict__ p2, unsigned short* __restrict__ p2t)
{
    __shared__ unsigned short tile[32][33];
    int b = blockIdx.z, s0 = blockIdx.x * 32, c0 = blockIdx.y * 32;
    #pragma unroll
    for (int j = 0; j < 4; ++j) {
        int c = threadIdx.y + j * 8;
        tile[c][threadIdx.x] = f2bf(p2[((size_t)b * C2_ + c0 + c) * S_ + s0 + threadIdx.x]);
    }
    __syncthreads();
    #pragma unroll
    for (int j = 0; j < 4; ++j) {
        int s = threadIdx.y + j * 8;
        p2t[((size_t)b * S_ + s0 + s) * C2_ + c0 + threadIdx.x] = tile[threadIdx.x][s];
    }
}

// ---------- build X1 (B,N,384) bf16, k-contiguous ----------
__global__ __launch_bounds__(256) void build_x1_kernel(
    const float* __restrict__ points1,            // (B,128,N) fp32
    const unsigned short* __restrict__ p2t,       // (B,S,256) bf16
    const int* __restrict__ idx, const float* __restrict__ wts,
    const float* __restrict__ te1,                // (B,384) f32
    unsigned short* __restrict__ X1)
{
    int b = blockIdx.y;
    int n = blockIdx.x * 256 + threadIdx.x;
    size_t base3 = ((size_t)b * N_ + n) * 3;
    int j0 = idx[base3], j1 = idx[base3 + 1], j2 = idx[base3 + 2];
    float w0 = wts[base3], w1 = wts[base3 + 1], w2 = wts[base3 + 2];
    unsigned short* xr = X1 + ((size_t)b * N_ + n) * CIN_;
    const float* te = te1 + b * CIN_;

    for (int c = 0; c < C1_; c += 8) {
        union { short8 v; unsigned short u[8]; } pk;
        #pragma unroll
        for (int jj = 0; jj < 8; ++jj) {
            float v = points1[((size_t)b * C1_ + c + jj) * N_ + n] + te[c + jj];
            pk.u[jj] = f2bf(v);
        }
        *(short8*)&xr[c] = pk.v;
    }
    const unsigned short* r0 = p2t + ((size_t)b * S_ + j0) * C2_;
    const unsigned short* r1 = p2t + ((size_t)b * S_ + j1) * C2_;
    const unsigned short* r2 = p2t + ((size_t)b * S_ + j2) * C2_;
    for (int c = 0; c < C2_; c += 8) {
        union { short8 v; unsigned short u[8]; } a0, a1, a2, pk;
        a0.v = *(const short8*)&r0[c];
        a1.v = *(const short8*)&r1[c];
        a2.v = *(const short8*)&r2[c];
        #pragma unroll
        for (int jj = 0; jj < 8; ++jj) {
            float v = w0 * bf2f(a0.u[jj]) + w1 * bf2f(a1.u[jj]) + w2 * bf2f(a2.u[jj])
                    + te[C1_ + c + jj];
            pk.u[jj] = f2bf(v);
        }
        *(short8*)&xr[C1_ + c] = pk.v;
    }
}

// ---------- GEMM (m97-style, B^T input) with fused BN-stat accumulation ----------
// A: (256, K) row-major bf16.  X: (B, 8192, K) k-contiguous bf16.
// MODE 0: out[b][n][o] bf16.  MODE 1: out[b][o][n] bf16.
template <int K, int MODE>
__global__ __launch_bounds__(256) void gemm_bt(
    const unsigned short* __restrict__ A,
    const unsigned short* __restrict__ X,
    const float* __restrict__ bias,
    unsigned short* __restrict__ out,
    float* __restrict__ sum, float* __restrict__ sq)
{
    __shared__ unsigned short sA[128 * 64];
    __shared__ unsigned short sB[128 * 64];
    const int tid = threadIdx.x;
    const int lane = tid & 63, wave = tid >> 6;
    const int wo = wave >> 1, wm = wave & 1;
    const int quad = lane >> 4, col = lane & 15;
    const int b = blockIdx.z;
    const int o0 = blockIdx.y * 128;
    const int n0 = blockIdx.x * 128;
    const unsigned short* Xb = X + (size_t)b * N_ * K;

    f32x4 acc[4][4];
    #pragma unroll
    for (int i = 0; i < 4; ++i)
        #pragma unroll
        for (int j = 0; j < 4; ++j) acc[i][j] = (f32x4){0.f, 0.f, 0.f, 0.f};

    for (int k0 = 0; k0 < K; k0 += 64) {
        #pragma unroll
        for (int i = 0; i < 4; ++i) {
            int chunk = i * 256 + tid;
            int row = chunk >> 3, c8 = chunk & 7;
            async16(&A [(o0 + row) * K + k0 + c8 * 8], &sA[chunk * 8]);
            async16(&Xb[(size_t)(n0 + row) * K + k0 + c8 * 8], &sB[chunk * 8]);
        }
        __syncthreads();
        #pragma unroll
        for (int kk = 0; kk < 64; kk += 32) {
            short8 af[4], bfr[4];
            #pragma unroll
            for (int i = 0; i < 4; ++i)
                af[i] = *(const short8*)&sA[(wo * 64 + i * 16 + col) * 64 + kk + quad * 8];
            #pragma unroll
            for (int j = 0; j < 4; ++j)
                bfr[j] = *(const short8*)&sB[(wm * 64 + j * 16 + col) * 64 + kk + quad * 8];
            #pragma unroll
            for (int i = 0; i < 4; ++i)
                #pragma unroll
                for (int j = 0; j < 4; ++j)
                    acc[i][j] = __builtin_amdgcn_mfma_f32_16x16x32_bf16(af[i], bfr[j], acc[i][j], 0, 0, 0);
        }
        __syncthreads();
    }

    #pragma unroll
    for (int i = 0; i < 4; ++i) {
        int oo = o0 + wo * 64 + i * 16 + quad * 4;
        float bv0 = bias[oo + 0], bv1 = bias[oo + 1];
        float bv2 = bias[oo + 2], bv3 = bias[oo + 3];
        float s0 = 0.f, s1 = 0.f, s2 = 0.f, s3 = 0.f;
        float q0 = 0.f, q1 = 0.f, q2 = 0.f, q3 = 0.f;
        #pragma unroll
        for (int j = 0; j < 4; ++j) {
            int nn = n0 + wm * 64 + j * 16 + col;
            float v0 = acc[i][j][0] + bv0, v1 = acc[i][j][1] + bv1;
            float v2 = acc[i][j][2] + bv2, v3 = acc[i][j][3] + bv3;
            s0 += v0; q0 += v0 * v0; s1 += v1; q1 += v1 * v1;
            s2 += v2; q2 += v2 * v2; s3 += v3; q3 += v3 * v3;
            if (MODE == 0) {
                union { unsigned short u[4]; uint2 p; } pk;
                pk.u[0] = f2bf(v0); pk.u[1] = f2bf(v1);
                pk.u[2] = f2bf(v2); pk.u[3] = f2bf(v3);
                *(uint2*)&out[((size_t)b * N_ + nn) * CO_ + oo] = pk.p;
            } else {
                out[((size_t)b * CO_ + oo + 0) * N_ + nn] = f2bf(v0);
                out[((size_t)b * CO_ + oo + 1) * N_ + nn] = f2bf(v1);
                out[((size_t)b * CO_ + oo + 2) * N_ + nn] = f2bf(v2);
                out[((size_t)b * CO_ + oo + 3) * N_ + nn] = f2bf(v3);
            }
        }
        // reduce the 16 col-lanes of this quad, then one atomic per channel
        #pragma unroll
        for (int off = 1; off < 16; off <<= 1) {
            s0 += __shfl_down(s0, off); q0 += __shfl_down(q0, off);
            s1 += __shfl_down(s1, off); q1 += __shfl_down(q1, off);
            s2 += __shfl_down(s2, off); q2 += __shfl_down(q2, off);
            s3 += __shfl_down(s3, off); q3 += __shfl_down(q3, off);
        }
        if (col == 0) {
            atomicAdd(&sum[oo + 0], s0); atomicAdd(&sq[oo + 0], q0);
            atomicAdd(&sum[oo + 1], s1); atomicAdd(&sq[oo + 1], q1);
            atomicAdd(&sum[oo + 2], s2); atomicAdd(&sq[oo + 2], q2);
            atomicAdd(&sum[oo + 3], s3); atomicAdd(&sq[oo + 3], q3);
        }
    }
}

// ---------- BN params ----------
__global__ void bnparam_kernel(const float* __restrict__ sum, const float* __restrict__ sq,
                               const float* __restrict__ gamma,
                               const float* __restrict__ beta,
                               float* __restrict__ scale, float* __restrict__ shift)
{
    int o = threadIdx.x;
    const float inv = 1.0f / 65536.0f;
    float m = sum[o] * inv;
    float var = fmaxf(sq[o] * inv - m * m, 0.f);
    float sc = gamma[o] / sqrtf(var + 1e-5f);
    scale[o] = sc;
    shift[o] = beta[o] - m * sc;
}

// ---------- in-place: x2 = gelu(scale*y + shift) + te2, layout (B,N,256) bf16 ----------
__global__ __launch_bounds__(256) void apply1_kernel(
    unsigned short* __restrict__ y, const float* __restrict__ scale,
    const float* __restrict__ shift, const float* __restrict__ te2)
{
    __shared__ float ssc[CO_], ssh[CO_], ste[CO_];
    int b = blockIdx.x >> 10;             // 1024 blocks per batch
    int t = threadIdx.x;
    ssc[t] = scale[t]; ssh[t] = shift[t]; ste[t] = te2[b * CO_ + t];
    __syncthreads();
    int g = blockIdx.x * 256 + t;
    int row = g >> 5;
    int og = (g & 31) * 8;
    unsigned short* p = y + (size_t)row * CO_ + og;
    union { short8 v; unsigned short u[8]; } in, op;
    in.v = *(short8*)p;
    #pragma unroll
    for (int jj = 0; jj < 8; ++jj) {
        int o = og + jj;
        op.u[jj] = f2bf(gelu_f(ssc[o] * bf2f(in.u[jj]) + ssh[o]) + ste[o]);
    }
    *(short8*)p = op.v;
}

// ---------- final: out = gelu(scale*z + shift), layout (B,256,N), fp32 out ----------
__global__ __launch_bounds__(256) void final_kernel(
    const unsigned short* __restrict__ z, const float* __restrict__ scale,
    const float* __restrict__ shift, float* __restrict__ out)
{
    int g = blockIdx.x * 256 + threadIdx.x;
    size_t e = (size_t)g * 8;
    int row = (int)(e >> 13);
    int o = row & (CO_ - 1);
    float sc = scale[o], sh = shift[o];
    union { short8 v; unsigned short u[8]; } in;
    in.v = *(const short8*)&z[e];
    float vo[8];
    #pragma unroll
    for (int jj = 0; jj < 8; ++jj)
        vo[jj] = gelu_f(sc * bf2f(in.u[jj]) + sh);
    *(float4*)&out[e]     = make_float4(vo[0], vo[1], vo[2], vo[3]);
    *(float4*)&out[e + 4] = make_float4(vo[4], vo[5], vo[6], vo[7]);
}

// ---------- launch ----------
extern "C" void kernel_launch(void* const* d_in, const int* in_sizes, int n_in,
                              void* d_out, int out_size, void* d_ws, size_t ws_size,
                              hipStream_t stream)
{
    (void)in_sizes; (void)n_in; (void)out_size; (void)ws_size;
    const float* xyz1    = (const float*)d_in[0];
    const float* xyz2    = (const float*)d_in[1];
    const float* points1 = (const float*)d_in[2];
    const float* points2 = (const float*)d_in[3];
    const float* t_embed = (const float*)d_in[4];
    const float* w_t1    = (const float*)d_in[5];
    const float* b_t1    = (const float*)d_in[6];
    const float* w_c1    = (const float*)d_in[7];
    const float* b_c1    = (const float*)d_in[8];
    const float* g1      = (const float*)d_in[9];
    const float* be1     = (const float*)d_in[10];
    const float* w_t2    = (const float*)d_in[11];
    const float* b_t2    = (const float*)d_in[12];
    const float* w_c2    = (const float*)d_in[13];
    const float* b_c2    = (const float*)d_in[14];
    const float* g2      = (const float*)d_in[15];
    const float* be2     = (const float*)d_in[16];

    char* w = (char*)d_ws;
    float* te1        = (float*)(w + OFF_TE1);
    float* te2        = (float*)(w + OFF_TE2);
    float* s1_sum     = (float*)(w + OFF_STATS);
    float* s1_sq      = s1_sum + 256;
    float* s2_sum     = s1_sum + 512;
    float* s2_sq      = s1_sum + 768;
    float* scale1     = (float*)(w + OFF_BN1);
    float* shift1     = scale1 + 256;
    float* scale2     = (float*)(w + OFF_BN2);
    float* shift2     = scale2 + 256;
    int*   idx        = (int*)(w + OFF_IDX);
    float* wts        = (float*)(w + OFF_WTS);
    unsigned short* wc1 = (unsigned short*)(w + OFF_WC1);
    unsigned short* wc2 = (unsigned short*)(w + OFF_WC2);
    unsigned short* p2t = (unsigned short*)(w + OFF_P2T);
    float* pd         = (float*)(w + OFF_PD);
    int*   pi         = (int*)(w + OFF_PI);
    unsigned short* X1  = (unsigned short*)(w + OFF_X1);
    unsigned short* Z   = (unsigned short*)(w + OFF_X1);   // reuse X1 region after gemm1
    unsigned short* Y   = (unsigned short*)(w + OFF_Y);
    float* out = (float*)d_out;

    hipMemsetAsync(w + OFF_STATS, 0, 4096, stream);

    hipLaunchKernelGGL(wcvt_kernel, dim3(CIN_ * CO_ / 256), dim3(256), 0, stream,
                       w_c1, w_c2, wc1, wc2);
    hipLaunchKernelGGL(te_kernel, dim3(B_), dim3(640), 0, stream,
                       t_embed, w_t1, b_t1, w_t2, b_t2, te1, te2);
    hipLaunchKernelGGL(knn_part_kernel, dim3(N_ / KQB, KCH, B_), dim3(256), 0, stream,
                       xyz1, xyz2, pd, pi);
    hipLaunchKernelGGL(knn_merge_kernel, dim3(B_ * N_ / 256), dim3(256), 0, stream,
                       pd, pi, idx, wts);
    hipLaunchKernelGGL(transpose_p2, dim3(S_ / 32, C2_ / 32, B_), dim3(32, 8), 0, stream,
                       points2, p2t);
    hipLaunchKernelGGL(build_x1_kernel, dim3(N_ / 256, B_), dim3(256), 0, stream,
                       points1, p2t, idx, wts, te1, X1);
    hipLaunchKernelGGL((gemm_bt<CIN_, 0>), dim3(N_ / 128, CO_ / 128, B_), dim3(256), 0, stream,
                       wc1, X1, b_c1, Y, s1_sum, s1_sq);
    hipLaunchKernelGGL(bnparam_kernel, dim3(1), dim3(256), 0, stream,
                       s1_sum, s1_sq, g1, be1, scale1, shift1);
    hipLaunchKernelGGL(apply1_kernel, dim3(8192), dim3(256), 0, stream,
                       Y, scale1, shift1, te2);
    hipLaunchKernelGGL((gemm_bt<CO_, 1>), dim3(N_ / 128, CO_ / 128, B_), dim3(256), 0, stream,
                       wc2, Y, b_c2, Z, s2_sum, s2_sq);
    hipLaunchKernelGGL(bnparam_kernel, dim3(1), dim3(256), 0, stream,
                       s2_sum, s2_sq, g2, be2, scale2, shift2);
    hipLaunchKernelGGL(final_kernel, dim3(8192), dim3(256), 0, stream,
                       Z, scale2, shift2, out);
}

// Round 4
// 413.739 us; speedup vs baseline: 1.4273x; 1.4273x over previous
//
#include <hip/hip_runtime.h>
#include <cfloat>
#include <cmath>

#define B_   8
#define N_   8192
#define S_   2048
#define C1_  128
#define C2_  256
#define T_   256
#define CIN_ 384
#define CO_  256

#define KCH  8           // knn S-chunks
#define KCS  (S_ / KCH)  // 256 candidates per chunk
#define KQB  512         // queries per knn block (256 thr x 2 queries)

typedef __attribute__((ext_vector_type(8))) short short8;
typedef __attribute__((ext_vector_type(4))) float f32x4;

// ---------- helpers ----------
__device__ __forceinline__ float bf2f(unsigned short u) {
    union { unsigned int i; float f; } v; v.i = ((unsigned int)u) << 16; return v.f;
}
__device__ __forceinline__ unsigned short f2bf(float f) {
    union { float f; unsigned int i; } v; v.f = f;
    unsigned int i = v.i;
    unsigned int r = i + 0x7FFFu + ((i >> 16) & 1u);   // RNE
    return (unsigned short)(r >> 16);
}
__device__ __forceinline__ float gelu_f(float x) {
    return 0.5f * x * (1.0f + erff(x * 0.70710678118654752440f));
}
__device__ __forceinline__ void async16(const void* g, void* l) {
    __builtin_amdgcn_global_load_lds((const __attribute__((address_space(1))) void*)g,
                                     (__attribute__((address_space(3))) void*)l, 16, 0, 0);
}

// ---------- ws layout (bytes) ----------
#define OFF_TE1   0u
#define OFF_TE2   16384u
#define OFF_BN1   28672u      // scale1(1024) shift1(1024)
#define OFF_BN2   30720u
#define OFF_IDX   32768u      // 65536*3*4 = 786432
#define OFF_WTS   819200u     // 786432
#define OFF_WC1   1605632u    // 98304*2
#define OFF_WC2   1802240u    // 65536*2  (ends 1933312)
#define OFF_RS    1933312u    // row stats layer2: 2048*4*2 = 16384
#define OFF_P2T   2097152u    // 8*2048*256*2 = 8388608 (bf16)
#define OFF_X1    10485760u   // 8*8192*384*2 = 50331648 (bf16; Z + knn/stat partials reuse)
#define OFF_Y     60817408u   // 8*8192*256*2 = 33554432 (bf16)
// transient tenants of the X1 region (each consumed before X1/Z overwrites):
#define OFF_PD    OFF_X1                    // knn dist partials  6291456
#define OFF_PI    (OFF_X1 + 6291456u)       // knn idx partials   6291456
#define OFF_PS1   OFF_X1                    // stats1 psum 512*256*4 = 524288
#define OFF_PQ1   (OFF_X1 + 524288u)        // stats1 psq  524288

// ---------- weight fp32 -> bf16 ----------
__global__ __launch_bounds__(256) void wcvt_kernel(
    const float* __restrict__ w1, const float* __restrict__ w2,
    unsigned short* __restrict__ o1, unsigned short* __restrict__ o2)
{
    int g = blockIdx.x * 256 + threadIdx.x;          // grid 384*256 = 98304
    o1[g] = f2bf(w1[g]);
    if (g < CO_ * CO_) o2[g] = f2bf(w2[g]);
}

// ---------- te1/te2 ----------
__global__ __launch_bounds__(640) void te_kernel(
    const float* __restrict__ t_embed,
    const float* __restrict__ w_t1, const float* __restrict__ b_t1,
    const float* __restrict__ w_t2, const float* __restrict__ b_t2,
    float* __restrict__ te1, float* __restrict__ te2)
{
    __shared__ float gt[T_];
    int b = blockIdx.x, t = threadIdx.x;
    if (t < T_) gt[t] = gelu_f(t_embed[b * T_ + t]);
    __syncthreads();
    if (t < CIN_) {
        const float* w = w_t1 + t * T_;
        float s = 0.f;
        for (int k = 0; k < T_; ++k) s += gt[k] * w[k];
        te1[b * CIN_ + t] = s + b_t1[t];
    } else {
        int o = t - CIN_;
        const float* w = w_t2 + o * T_;
        float s = 0.f;
        for (int k = 0; k < T_; ++k) s += gt[k] * w[k];
        te2[b * CO_ + o] = s + b_t2[o];
    }
}

// ---------- 3-NN partials: per S-chunk top-3 ----------
__global__ __launch_bounds__(256) void knn_part_kernel(
    const float* __restrict__ xyz1, const float* __restrict__ xyz2,
    float* __restrict__ pd, int* __restrict__ pi)
{
    __shared__ float4 sp[KCS];   // 4 KB
    int b = blockIdx.z, ch = blockIdx.y, tid = threadIdx.x;
    int s0 = ch * KCS;
    {
        int gs = s0 + tid;
        float x = xyz2[(b * S_ + gs) * 3 + 0];
        float y = xyz2[(b * S_ + gs) * 3 + 1];
        float z = xyz2[(b * S_ + gs) * 3 + 2];
        sp[tid] = make_float4(x, y, z, x * x + y * y + z * z);
    }
    __syncthreads();

    float x1[2], y1[2], z1[2], n1[2];
    float d1[2], d2[2], d3[2];
    int   i1[2], i2[2], i3[2];
    #pragma unroll
    for (int qq = 0; qq < 2; ++qq) {
        int n = blockIdx.x * KQB + qq * 256 + tid;
        x1[qq] = xyz1[(b * N_ + n) * 3 + 0];
        y1[qq] = xyz1[(b * N_ + n) * 3 + 1];
        z1[qq] = xyz1[(b * N_ + n) * 3 + 2];
        n1[qq] = x1[qq] * x1[qq] + y1[qq] * y1[qq] + z1[qq] * z1[qq];
        d1[qq] = FLT_MAX; d2[qq] = FLT_MAX; d3[qq] = FLT_MAX;
        i1[qq] = 0; i2[qq] = 0; i3[qq] = 0;
    }

    #pragma unroll 2
    for (int s = 0; s < KCS; ++s) {
        float4 p = sp[s];
        int gi = s0 + s;
        #pragma unroll
        for (int qq = 0; qq < 2; ++qq) {
            float dot = x1[qq] * p.x + y1[qq] * p.y + z1[qq] * p.z;
            float d = (n1[qq] + p.w) - 2.0f * dot;
            if (d < d3[qq]) {
                if (d < d2[qq]) {
                    d3[qq] = d2[qq]; i3[qq] = i2[qq];
                    if (d < d1[qq]) { d2[qq] = d1[qq]; i2[qq] = i1[qq]; d1[qq] = d; i1[qq] = gi; }
                    else            { d2[qq] = d;      i2[qq] = gi; }
                } else { d3[qq] = d; i3[qq] = gi; }
            }
        }
    }

    #pragma unroll
    for (int qq = 0; qq < 2; ++qq) {
        int n = blockIdx.x * KQB + qq * 256 + tid;
        size_t pb = (((size_t)b * KCH + ch) * N_ + n) * 3;
        pd[pb + 0] = d1[qq]; pd[pb + 1] = d2[qq]; pd[pb + 2] = d3[qq];
        pi[pb + 0] = i1[qq]; pi[pb + 1] = i2[qq]; pi[pb + 2] = i3[qq];
    }
}

// ---------- merge chunk partials -> idx/wts ----------
__global__ __launch_bounds__(256) void knn_merge_kernel(
    const float* __restrict__ pd, const int* __restrict__ pi,
    int* __restrict__ idx, float* __restrict__ wts)
{
    int g = blockIdx.x * 256 + threadIdx.x;   // 65536
    int b = g >> 13, n = g & (N_ - 1);
    float d1 = FLT_MAX, d2 = FLT_MAX, d3 = FLT_MAX;
    int   i1 = 0, i2 = 0, i3 = 0;
    for (int ch = 0; ch < KCH; ++ch) {
        size_t pb = (((size_t)b * KCH + ch) * N_ + n) * 3;
        #pragma unroll
        for (int k = 0; k < 3; ++k) {
            float d = pd[pb + k];
            int   s = pi[pb + k];
            if (d < d3) {
                if (d < d2) {
                    d3 = d2; i3 = i2;
                    if (d < d1) { d2 = d1; i2 = i1; d1 = d; i1 = s; }
                    else        { d2 = d;  i2 = s; }
                } else { d3 = d; i3 = s; }
            }
        }
    }
    float r1 = 1.0f / (d1 + 1e-8f);
    float r2 = 1.0f / (d2 + 1e-8f);
    float r3 = 1.0f / (d3 + 1e-8f);
    float rs = 1.0f / (r1 + r2 + r3);
    size_t base = (size_t)g * 3;
    idx[base] = i1; idx[base + 1] = i2; idx[base + 2] = i3;
    wts[base] = r1 * rs; wts[base + 1] = r2 * rs; wts[base + 2] = r3 * rs;
}

// ---------- transpose points2 (B,C2,S) fp32 -> (B,S,C2) bf16 ----------
__global__ __launch_bounds__(256) void transpose_p2(
    const float* __restrict__ p2, unsigned short* __restrict__ p2t)
{
    __shared__ unsigned short tile[32][33];
    int b = blockIdx.z, s0 = blockIdx.x * 32, c0 = blockIdx.y * 32;
    #pragma unroll
    for (int j = 0; j < 4; ++j) {
        int c = threadIdx.y + j * 8;
        tile[c][threadIdx.x] = f2bf(p2[((size_t)b * C2_ + c0 + c) * S_ + s0 + threadIdx.x]);
    }
    __syncthreads();
    #pragma unroll
    for (int j = 0; j < 4; ++j) {
        int s = threadIdx.y + j * 8;
        p2t[((size_t)b * S_ + s0 + s) * C2_ + c0 + threadIdx.x] = tile[threadIdx.x][s];
    }
}

// ---------- build X1 (B,N,384) bf16, k-contiguous ----------
// 384 threads = 3 wave-pairs: ty0 -> p1 ch 0..127, ty1 -> p2 ch 0..127,
// ty2 -> p2 ch 128..255.  128 points per block, grid (64, 8) = 512 blocks.
__global__ __launch_bounds__(384) void build_x1_kernel(
    const float* __restrict__ points1,            // (B,128,N) fp32
    const unsigned short* __restrict__ p2t,       // (B,S,256) bf16
    const int* __restrict__ idx, const float* __restrict__ wts,
    const float* __restrict__ te1,                // (B,384) f32
    unsigned short* __restrict__ X1)
{
    int b = blockIdx.y;
    int tx = threadIdx.x & 127;
    int ty = threadIdx.x >> 7;      // wave-uniform (waves are 64 lanes)
    int n = blockIdx.x * 128 + tx;
    unsigned short* xr = X1 + ((size_t)b * N_ + n) * CIN_;
    const float* te = te1 + b * CIN_;

    if (ty == 0) {
        #pragma unroll
        for (int c = 0; c < C1_; c += 8) {
            union { short8 v; unsigned short u[8]; } pk;
            #pragma unroll
            for (int jj = 0; jj < 8; ++jj) {
                float v = points1[((size_t)b * C1_ + c + jj) * N_ + n] + te[c + jj];
                pk.u[jj] = f2bf(v);
            }
            *(short8*)&xr[c] = pk.v;
        }
    } else {
        size_t base3 = ((size_t)b * N_ + n) * 3;
        int j0 = idx[base3], j1 = idx[base3 + 1], j2 = idx[base3 + 2];
        float w0 = wts[base3], w1 = wts[base3 + 1], w2 = wts[base3 + 2];
        int cbase = (ty - 1) * 128;
        const unsigned short* r0 = p2t + ((size_t)b * S_ + j0) * C2_ + cbase;
        const unsigned short* r1 = p2t + ((size_t)b * S_ + j1) * C2_ + cbase;
        const unsigned short* r2 = p2t + ((size_t)b * S_ + j2) * C2_ + cbase;
        #pragma unroll
        for (int c = 0; c < 128; c += 8) {
            union { short8 v; unsigned short u[8]; } a0, a1, a2, pk;
            a0.v = *(const short8*)&r0[c];
            a1.v = *(const short8*)&r1[c];
            a2.v = *(const short8*)&r2[c];
            #pragma unroll
            for (int jj = 0; jj < 8; ++jj) {
                float v = w0 * bf2f(a0.u[jj]) + w1 * bf2f(a1.u[jj]) + w2 * bf2f(a2.u[jj])
                        + te[C1_ + cbase + c + jj];
                pk.u[jj] = f2bf(v);
            }
            *(short8*)&xr[C1_ + cbase + c] = pk.v;
        }
    }
}

// ---------- GEMM (m97-style, B^T input) ----------
// MODE 0: out[b][n][o] bf16.  MODE 1: out[b][o][n] bf16.  No atomics.
template <int K, int MODE>
__global__ __launch_bounds__(256) void gemm_bt(
    const unsigned short* __restrict__ A,
    const unsigned short* __restrict__ X,
    const float* __restrict__ bias,
    unsigned short* __restrict__ out)
{
    __shared__ unsigned short sA[128 * 64];
    __shared__ unsigned short sB[128 * 64];
    const int tid = threadIdx.x;
    const int lane = tid & 63, wave = tid >> 6;
    const int wo = wave >> 1, wm = wave & 1;
    const int quad = lane >> 4, col = lane & 15;
    const int b = blockIdx.z;
    const int o0 = blockIdx.y * 128;
    const int n0 = blockIdx.x * 128;
    const unsigned short* Xb = X + (size_t)b * N_ * K;

    f32x4 acc[4][4];
    #pragma unroll
    for (int i = 0; i < 4; ++i)
        #pragma unroll
        for (int j = 0; j < 4; ++j) acc[i][j] = (f32x4){0.f, 0.f, 0.f, 0.f};

    for (int k0 = 0; k0 < K; k0 += 64) {
        #pragma unroll
        for (int i = 0; i < 4; ++i) {
            int chunk = i * 256 + tid;
            int row = chunk >> 3, c8 = chunk & 7;
            async16(&A [(o0 + row) * K + k0 + c8 * 8], &sA[chunk * 8]);
            async16(&Xb[(size_t)(n0 + row) * K + k0 + c8 * 8], &sB[chunk * 8]);
        }
        __syncthreads();
        #pragma unroll
        for (int kk = 0; kk < 64; kk += 32) {
            short8 af[4], bfr[4];
            #pragma unroll
            for (int i = 0; i < 4; ++i)
                af[i] = *(const short8*)&sA[(wo * 64 + i * 16 + col) * 64 + kk + quad * 8];
            #pragma unroll
            for (int j = 0; j < 4; ++j)
                bfr[j] = *(const short8*)&sB[(wm * 64 + j * 16 + col) * 64 + kk + quad * 8];
            #pragma unroll
            for (int i = 0; i < 4; ++i)
                #pragma unroll
                for (int j = 0; j < 4; ++j)
                    acc[i][j] = __builtin_amdgcn_mfma_f32_16x16x32_bf16(af[i], bfr[j], acc[i][j], 0, 0, 0);
        }
        __syncthreads();
    }

    #pragma unroll
    for (int i = 0; i < 4; ++i) {
        int oo = o0 + wo * 64 + i * 16 + quad * 4;
        float bv0 = bias[oo + 0], bv1 = bias[oo + 1];
        float bv2 = bias[oo + 2], bv3 = bias[oo + 3];
        #pragma unroll
        for (int j = 0; j < 4; ++j) {
            int nn = n0 + wm * 64 + j * 16 + col;
            float v0 = acc[i][j][0] + bv0, v1 = acc[i][j][1] + bv1;
            float v2 = acc[i][j][2] + bv2, v3 = acc[i][j][3] + bv3;
            if (MODE == 0) {
                union { unsigned short u[4]; uint2 p; } pk;
                pk.u[0] = f2bf(v0); pk.u[1] = f2bf(v1);
                pk.u[2] = f2bf(v2); pk.u[3] = f2bf(v3);
                *(uint2*)&out[((size_t)b * N_ + nn) * CO_ + oo] = pk.p;
            } else {
                out[((size_t)b * CO_ + oo + 0) * N_ + nn] = f2bf(v0);
                out[((size_t)b * CO_ + oo + 1) * N_ + nn] = f2bf(v1);
                out[((size_t)b * CO_ + oo + 2) * N_ + nn] = f2bf(v2);
                out[((size_t)b * CO_ + oo + 3) * N_ + nn] = f2bf(v3);
            }
        }
    }
}

// ---------- stats layer1: per-block partials over (n,o)-major Y ----------
__global__ __launch_bounds__(256) void stats1_part_kernel(
    const unsigned short* __restrict__ y, float* __restrict__ psum, float* __restrict__ psq)
{
    int t = threadIdx.x;
    int r0 = blockIdx.x * 128;              // 512 blocks
    float s = 0.f, q = 0.f;
    for (int r = r0; r < r0 + 128; ++r) {
        float v = bf2f(y[(size_t)r * CO_ + t]);
        s += v; q += v * v;
    }
    psum[blockIdx.x * CO_ + t] = s;
    psq [blockIdx.x * CO_ + t] = q;
}

// ---------- reduce stats1 partials + bn params (deterministic, no atomics) ----------
__global__ __launch_bounds__(256) void bn_reduce1_kernel(
    const float* __restrict__ psum, const float* __restrict__ psq,
    const float* __restrict__ gamma, const float* __restrict__ beta,
    float* __restrict__ scale, float* __restrict__ shift)
{
    __shared__ float ls[4][64], lq[4][64];
    int l = threadIdx.x & 63;
    int seg = threadIdx.x >> 6;
    int ch = blockIdx.x * 64 + l;           // grid 4
    float s = 0.f, q = 0.f;
    for (int r = seg * 128; r < seg * 128 + 128; ++r) {
        s += psum[r * CO_ + ch];
        q += psq [r * CO_ + ch];
    }
    ls[seg][l] = s; lq[seg][l] = q;
    __syncthreads();
    if (seg == 0) {
        s = ls[0][l] + ls[1][l] + ls[2][l] + ls[3][l];
        q = lq[0][l] + lq[1][l] + lq[2][l] + lq[3][l];
        const float inv = 1.0f / 65536.0f;
        float m = s * inv;
        float var = fmaxf(q * inv - m * m, 0.f);
        float sc = gamma[ch] / sqrtf(var + 1e-5f);
        scale[ch] = sc;
        shift[ch] = beta[ch] - m * sc;
    }
}

// ---------- stats layer2: per-(b,o)-row sums over Z (o,n)-major ----------
__global__ __launch_bounds__(256) void stats2_part_kernel(
    const unsigned short* __restrict__ z, float* __restrict__ rs, float* __restrict__ rq)
{
    __shared__ float ws_[4], wq_[4];
    int row = blockIdx.x;                   // 2048
    const unsigned short* zr = z + (size_t)row * N_;
    int t = threadIdx.x;
    float s = 0.f, q = 0.f;
    for (int i = t * 8; i < N_; i += 2048) {
        union { short8 v; unsigned short u[8]; } in;
        in.v = *(const short8*)&zr[i];
        #pragma unroll
        for (int jj = 0; jj < 8; ++jj) {
            float v = bf2f(in.u[jj]); s += v; q += v * v;
        }
    }
    for (int off = 32; off > 0; off >>= 1) { s += __shfl_down(s, off); q += __shfl_down(q, off); }
    int lane = t & 63, wv = t >> 6;
    if (lane == 0) { ws_[wv] = s; wq_[wv] = q; }
    __syncthreads();
    if (t == 0) {
        rs[row] = ws_[0] + ws_[1] + ws_[2] + ws_[3];
        rq[row] = wq_[0] + wq_[1] + wq_[2] + wq_[3];
    }
}

// ---------- reduce stats2 rows + bn params ----------
__global__ __launch_bounds__(256) void bn_reduce2_kernel(
    const float* __restrict__ rs, const float* __restrict__ rq,
    const float* __restrict__ gamma, const float* __restrict__ beta,
    float* __restrict__ scale, float* __restrict__ shift)
{
    int o = threadIdx.x;                    // 1 block, 256 threads
    float s = 0.f, q = 0.f;
    #pragma unroll
    for (int b = 0; b < B_; ++b) { s += rs[b * CO_ + o]; q += rq[b * CO_ + o]; }
    const float inv = 1.0f / 65536.0f;
    float m = s * inv;
    float var = fmaxf(q * inv - m * m, 0.f);
    float sc = gamma[o] / sqrtf(var + 1e-5f);
    scale[o] = sc;
    shift[o] = beta[o] - m * sc;
}

// ---------- in-place: x2 = gelu(scale*y + shift) + te2, layout (B,N,256) bf16 ----------
__global__ __launch_bounds__(256) void apply1_kernel(
    unsigned short* __restrict__ y, const float* __restrict__ scale,
    const float* __restrict__ shift, const float* __restrict__ te2)
{
    __shared__ float ssc[CO_], ssh[CO_], ste[CO_];
    int b = blockIdx.x >> 10;
    int t = threadIdx.x;
    ssc[t] = scale[t]; ssh[t] = shift[t]; ste[t] = te2[b * CO_ + t];
    __syncthreads();
    int g = blockIdx.x * 256 + t;
    int row = g >> 5;
    int og = (g & 31) * 8;
    unsigned short* p = y + (size_t)row * CO_ + og;
    union { short8 v; unsigned short u[8]; } in, op;
    in.v = *(short8*)p;
    #pragma unroll
    for (int jj = 0; jj < 8; ++jj) {
        int o = og + jj;
        op.u[jj] = f2bf(gelu_f(ssc[o] * bf2f(in.u[jj]) + ssh[o]) + ste[o]);
    }
    *(short8*)p = op.v;
}

// ---------- final: out = gelu(scale*z + shift), layout (B,256,N), fp32 out ----------
__global__ __launch_bounds__(256) void final_kernel(
    const unsigned short* __restrict__ z, const float* __restrict__ scale,
    const float* __restrict__ shift, float* __restrict__ out)
{
    int g = blockIdx.x * 256 + threadIdx.x;
    size_t e = (size_t)g * 8;
    int row = (int)(e >> 13);
    int o = row & (CO_ - 1);
    float sc = scale[o], sh = shift[o];
    union { short8 v; unsigned short u[8]; } in;
    in.v = *(const short8*)&z[e];
    float vo[8];
    #pragma unroll
    for (int jj = 0; jj < 8; ++jj)
        vo[jj] = gelu_f(sc * bf2f(in.u[jj]) + sh);
    *(float4*)&out[e]     = make_float4(vo[0], vo[1], vo[2], vo[3]);
    *(float4*)&out[e + 4] = make_float4(vo[4], vo[5], vo[6], vo[7]);
}

// ---------- launch ----------
extern "C" void kernel_launch(void* const* d_in, const int* in_sizes, int n_in,
                              void* d_out, int out_size, void* d_ws, size_t ws_size,
                              hipStream_t stream)
{
    (void)in_sizes; (void)n_in; (void)out_size; (void)ws_size;
    const float* xyz1    = (const float*)d_in[0];
    const float* xyz2    = (const float*)d_in[1];
    const float* points1 = (const float*)d_in[2];
    const float* points2 = (const float*)d_in[3];
    const float* t_embed = (const float*)d_in[4];
    const float* w_t1    = (const float*)d_in[5];
    const float* b_t1    = (const float*)d_in[6];
    const float* w_c1    = (const float*)d_in[7];
    const float* b_c1    = (const float*)d_in[8];
    const float* g1      = (const float*)d_in[9];
    const float* be1     = (const float*)d_in[10];
    const float* w_t2    = (const float*)d_in[11];
    const float* b_t2    = (const float*)d_in[12];
    const float* w_c2    = (const float*)d_in[13];
    const float* b_c2    = (const float*)d_in[14];
    const float* g2      = (const float*)d_in[15];
    const float* be2     = (const float*)d_in[16];

    char* w = (char*)d_ws;
    float* te1        = (float*)(w + OFF_TE1);
    float* te2        = (float*)(w + OFF_TE2);
    float* scale1     = (float*)(w + OFF_BN1);
    float* shift1     = scale1 + 256;
    float* scale2     = (float*)(w + OFF_BN2);
    float* shift2     = scale2 + 256;
    int*   idx        = (int*)(w + OFF_IDX);
    float* wts        = (float*)(w + OFF_WTS);
    unsigned short* wc1 = (unsigned short*)(w + OFF_WC1);
    unsigned short* wc2 = (unsigned short*)(w + OFF_WC2);
    float* rs         = (float*)(w + OFF_RS);
    float* rq         = rs + 2048;
    unsigned short* p2t = (unsigned short*)(w + OFF_P2T);
    float* pd         = (float*)(w + OFF_PD);
    int*   pi         = (int*)(w + OFF_PI);
    float* ps1        = (float*)(w + OFF_PS1);
    float* pq1        = (float*)(w + OFF_PQ1);
    unsigned short* X1  = (unsigned short*)(w + OFF_X1);
    unsigned short* Z   = (unsigned short*)(w + OFF_X1);
    unsigned short* Y   = (unsigned short*)(w + OFF_Y);
    float* out = (float*)d_out;

    hipLaunchKernelGGL(wcvt_kernel, dim3(CIN_ * CO_ / 256), dim3(256), 0, stream,
                       w_c1, w_c2, wc1, wc2);
    hipLaunchKernelGGL(te_kernel, dim3(B_), dim3(640), 0, stream,
                       t_embed, w_t1, b_t1, w_t2, b_t2, te1, te2);
    hipLaunchKernelGGL(knn_part_kernel, dim3(N_ / KQB, KCH, B_), dim3(256), 0, stream,
                       xyz1, xyz2, pd, pi);
    hipLaunchKernelGGL(knn_merge_kernel, dim3(B_ * N_ / 256), dim3(256), 0, stream,
                       pd, pi, idx, wts);
    hipLaunchKernelGGL(transpose_p2, dim3(S_ / 32, C2_ / 32, B_), dim3(32, 8), 0, stream,
                       points2, p2t);
    hipLaunchKernelGGL(build_x1_kernel, dim3(N_ / 128, B_), dim3(384), 0, stream,
                       points1, p2t, idx, wts, te1, X1);
    hipLaunchKernelGGL((gemm_bt<CIN_, 0>), dim3(N_ / 128, CO_ / 128, B_), dim3(256), 0, stream,
                       wc1, X1, b_c1, Y);
    hipLaunchKernelGGL(stats1_part_kernel, dim3(512), dim3(256), 0, stream, Y, ps1, pq1);
    hipLaunchKernelGGL(bn_reduce1_kernel, dim3(4), dim3(256), 0, stream,
                       ps1, pq1, g1, be1, scale1, shift1);
    hipLaunchKernelGGL(apply1_kernel, dim3(8192), dim3(256), 0, stream,
                       Y, scale1, shift1, te2);
    hipLaunchKernelGGL((gemm_bt<CO_, 1>), dim3(N_ / 128, CO_ / 128, B_), dim3(256), 0, stream,
                       wc2, Y, b_c2, Z);
    hipLaunchKernelGGL(stats2_part_kernel, dim3(B_ * CO_), dim3(256), 0, stream, Z, rs, rq);
    hipLaunchKernelGGL(bn_reduce2_kernel, dim3(1), dim3(256), 0, stream,
                       rs, rq, g2, be2, scale2, shift2);
    hipLaunchKernelGGL(final_kernel, dim3(8192), dim3(256), 0, stream,
                       Z, scale2, shift2, out);
}